// Round 11
// baseline (257.920 us; speedup 1.0000x reference)
//
#include <hip/hip_runtime.h>
#include <math.h>

#define NDIM 64
#define LRELU_SLOPE 0.2f
#define BSHIFT 10              // 1024 nodes per bucket
#define BNODES 1024
#define ECAP 12288             // edge capacity per bucket (mean ~10204, ~20 sigma headroom)
#define CCAP (ECAP + BNODES)   // csr capacity per bucket (edges + self loops)

typedef float f32x2 __attribute__((ext_vector_type(2)));

__device__ __forceinline__ ushort f2bf(float f) {
    unsigned u = __float_as_uint(f);
    unsigned r = (u + 0x7fffu + ((u >> 16) & 1u)) >> 16;   // RTNE
    return (ushort)r;
}
__device__ __forceinline__ float bflo(unsigned u) { return __uint_as_float(u << 16); }
__device__ __forceinline__ float bfhi(unsigned u) { return __uint_as_float(u & 0xffff0000u); }

// ---------------- partition edges into dst-buckets (packed u32 dl<<17|s) ---
// Requires N < 131072 (s fits 17 bits); dl < 1024 (10 bits). bcur is 0-based
// (zeroed by memset); slot = b*ECAP + reserved + local.
__global__ __launch_bounds__(256) void part_kernel(
    const int* __restrict__ src, const int* __restrict__ dst,
    int* __restrict__ bcur, unsigned* __restrict__ part,
    int E, int nb) {
    __shared__ int hist[128];
    __shared__ int base[128];
    int t = threadIdx.x;
    for (int i = t; i < nb; i += 256) hist[i] = 0;
    __syncthreads();
    int chunk = blockIdx.x * 4096;
    int s[16], d[16];
#pragma unroll
    for (int j = 0; j < 4; ++j) {
        int idx = chunk + j * 1024 + t * 4;
        if (idx + 3 < E) {
            int4 sv = *(const int4*)(src + idx);
            int4 dv = *(const int4*)(dst + idx);
            s[j*4+0]=sv.x; s[j*4+1]=sv.y; s[j*4+2]=sv.z; s[j*4+3]=sv.w;
            d[j*4+0]=dv.x; d[j*4+1]=dv.y; d[j*4+2]=dv.z; d[j*4+3]=dv.w;
        } else {
#pragma unroll
            for (int q = 0; q < 4; ++q) {
                int i2 = idx + q;
                if (i2 < E) { s[j*4+q] = src[i2]; d[j*4+q] = dst[i2]; }
                else        { s[j*4+q] = 0;       d[j*4+q] = -1; }
            }
        }
    }
#pragma unroll
    for (int j = 0; j < 16; ++j)
        if (d[j] >= 0) atomicAdd(&hist[d[j] >> BSHIFT], 1);
    __syncthreads();
    for (int i = t; i < nb; i += 256) {
        int c = hist[i];
        base[i] = c ? atomicAdd(&bcur[i], c) : 0;
        hist[i] = 0;          // reuse as running cursor
    }
    __syncthreads();
#pragma unroll
    for (int j = 0; j < 16; ++j) {
        if (d[j] >= 0) {
            int b = d[j] >> BSHIFT;
            int pos = base[b] + atomicAdd(&hist[b], 1);
            if (pos > ECAP - 1) pos = ECAP - 1;   // never fires statistically
            part[(size_t)b * ECAP + pos] =
                ((unsigned)(d[j] & (BNODES - 1)) << 17) | (unsigned)s[j];
        }
    }
}

// ---------------- per-bucket CSR build: 1024 nodes/bucket, 4 nodes/thread --
__global__ __launch_bounds__(256) void csr_kernel(
    const int* __restrict__ bcur, const unsigned* __restrict__ part,
    int* __restrict__ csr, int2* __restrict__ offlen, int N) {
    __shared__ int hist[1024];
    __shared__ int sc[256];
    int b = blockIdx.x, t = threadIdx.x;
    int nodeBase = b << BSHIFT;
    int nNodes = min(BNODES, N - nodeBase);
    int count = min(bcur[b], ECAP);
    for (int i = t; i < BNODES; i += 256) hist[i] = (i < nNodes) ? 1 : 0; // self-loop
    __syncthreads();
    const unsigned* slice = part + (size_t)b * ECAP;
    for (int i = t; i < count; i += 256)
        atomicAdd(&hist[slice[i] >> 17], 1);
    __syncthreads();
    // scan: 4 nodes per thread
    int c0 = hist[t*4], c1 = hist[t*4+1], c2 = hist[t*4+2], c3 = hist[t*4+3];
    int sum = c0 + c1 + c2 + c3;
    sc[t] = sum;
    __syncthreads();
    for (int o = 1; o < 256; o <<= 1) {
        int v = sc[t];
        int u = (t >= o) ? sc[t - o] : 0;
        __syncthreads();
        sc[t] = v + u;
        __syncthreads();
    }
    int run = sc[t] - sum;               // exclusive over this thread's 4 nodes
    int boff = b * CCAP;
    int cnts[4] = {c0, c1, c2, c3};
#pragma unroll
    for (int q = 0; q < 4; ++q) {
        int nl = t * 4 + q;
        if (nl < nNodes) {
            offlen[nodeBase + nl] = make_int2(boff + run, cnts[q]);
            csr[boff + run] = nodeBase + nl;   // self loop first
        }
        int nrun = run + cnts[q];
        hist[nl] = run + 1;              // cursor after self loop
        run = nrun;
    }
    __syncthreads();
    for (int i = t; i < count; i += 256) {
        unsigned e = slice[i];
        int dl = (int)(e >> 17);
        int pos = boff + atomicAdd(&hist[dl], 1);
        csr[pos] = (int)(e & 0x1ffffu);
    }
}

// ---------------- j-split GEMM: 64 nodes/block, wave wid owns 16 dims ------
// h output is fp8-e4m3 (HW cvt), 16 u32-quads per node via pitch-17 LDS
// transpose. as/ad stay fp32.
template<int K, int KS, bool BF16IN>
__global__ __launch_bounds__(256) void gemm_kernel(
    const void* __restrict__ Xv, const float* __restrict__ W,
    const float* __restrict__ asrc, const float* __restrict__ adst,
    unsigned char* __restrict__ h, float* __restrict__ as_, float* __restrict__ ad_, int N) {
    __shared__ float xs[64 * KS];          // swizzled input tile
    __shared__ unsigned hsq[64 * 17];      // fp8 quad transpose buffer (4.4 KB)
    __shared__ float ps[2][4][64];         // as/ad partials
    int t = threadIdx.x;
    int base = blockIdx.x * 64;
    if (BF16IN) {
        const unsigned* X = (const unsigned*)Xv;   // K/2 uints per row
        for (int i = t; i < 64 * (K / 2); i += 256) {
            int nl = i / (K / 2), p = i - nl * (K / 2);
            int k = p * 2;
            int node = base + nl;
            unsigned u = (node < N) ? X[(size_t)node * (K / 2) + p] : 0u;
            xs[nl * KS + ((k + nl) & (KS - 1))] = bflo(u);
            xs[nl * KS + ((k + 1 + nl) & (KS - 1))] = bfhi(u);
        }
    } else {
        const float* X = (const float*)Xv;
        for (int i = t; i < 64 * KS; i += 256) {
            int nl = i / KS, k = i - nl * KS;
            int node = base + nl;
            float v = (k < K && node < N) ? X[(size_t)node * K + k] : 0.f;
            xs[nl * KS + ((k + nl) & (KS - 1))] = v;
        }
    }
    __syncthreads();
    int wid = __builtin_amdgcn_readfirstlane(t >> 6);   // force scalar
    int lane = t & 63;
    int node = base + lane;
    float acc[16];
#pragma unroll
    for (int j = 0; j < 16; ++j) acc[j] = 0.f;
    const float* Wg = W + wid * 16;
    const float* xrow = xs + lane * KS;
#pragma unroll 4
    for (int k = 0; k < K; ++k) {
        float xk = xrow[(k + lane) & (KS - 1)];
#pragma unroll
        for (int j = 0; j < 16; ++j)
            acc[j] = fmaf(xk, Wg[k * 64 + j], acc[j]);
    }
    // as/ad partials over this wave's 16 dims
    float s = 0.f, d = 0.f;
#pragma unroll
    for (int j = 0; j < 16; ++j) {
        s = fmaf(acc[j], asrc[wid * 16 + j], s);
        d = fmaf(acc[j], adst[wid * 16 + j], d);
    }
    ps[0][wid][lane] = s;
    ps[1][wid][lane] = d;
    // pack 4 dims -> 1 fp8 quad (u32), write swizzled
#pragma unroll
    for (int j = 0; j < 16; j += 4) {
        int q = (wid * 16 + j) >> 2;            // quad index 0..15
        int sp = (q + lane) & 15;
        int u = __builtin_amdgcn_cvt_pk_fp8_f32(acc[j], acc[j + 1], 0, false);
        u = __builtin_amdgcn_cvt_pk_fp8_f32(acc[j + 2], acc[j + 3], u, true);
        hsq[lane * 17 + sp] = (unsigned)u;
    }
    __syncthreads();
    if (wid == 0) {
        float s4 = ps[0][0][lane] + ps[0][1][lane] + ps[0][2][lane] + ps[0][3][lane];
        float d4 = ps[1][0][lane] + ps[1][1][lane] + ps[1][2][lane] + ps[1][3][lane];
        if (node < N) { as_[node] = s4; ad_[node] = d4; }
    }
    // coalesced fp8x4 store of the 64x64 tile (16 u32 per node)
    unsigned* hout = (unsigned*)h;
    for (int pass = 0; pass < 4; ++pass) {
        int row = pass * 16 + (t >> 4);
        int q = t & 15;
        int sp = (q + row) & 15;
        unsigned v = hsq[row * 17 + sp];
        int n2 = base + row;
        if (n2 < N) hout[(size_t)n2 * 16 + q] = v;
    }
}

// ---------------- fused softmax + weighted-gather aggregation --------------
// Wave per node; 4 groups of 16 lanes; group g handles edge i*4+g; lane loads
// 1 uint = 4 fp8 dims (group fetches the full 64 B row = one line). Softmax
// fused, no max-subtraction (bounded logits). Masked edges: -INF -> ex=0.
// den is per-group (identical across the 16 lanes of a group); the 2-hop
// shfl_xor(16/32) yields the full sum counted once -> inv = 1/den.
__global__ __launch_bounds__(256) void agg_kernel(
    const int2* __restrict__ offlen, const int* __restrict__ csr,
    const float* __restrict__ as_, const float* __restrict__ ad_,
    const unsigned char* __restrict__ hsrc, const float* __restrict__ bias,
    ushort* __restrict__ out, float* __restrict__ pool, int n, int mode) {
    __shared__ float psum[4][NDIM];
    int wid = threadIdx.x >> 6, lane = threadIdx.x & 63;
    int g = lane >> 4, l = lane & 15;
    int wave = blockIdx.x * 4 + wid;
    float v0 = 0.f, v1 = 0.f, v2 = 0.f, v3 = 0.f;
    if (wave < n) {
        int2 ol = offlen[wave];
        int off = ol.x, len = ol.y;
        float adi = ad_[wave];
        float acc0 = 0.f, acc1 = 0.f, acc2 = 0.f, acc3 = 0.f, den = 0.f;
        int niter = (len + 3) >> 2;
        int e0 = g, e1 = 4 + g;
        bool ve0 = e0 < len, ve1 = e1 < len;
        int sk0 = ve0 ? csr[off + e0] : 0;
        int sk1 = ve1 ? csr[off + e1] : 0;
        float a0 = ve0 ? as_[sk0] : -INFINITY;
        unsigned hv0 = ve0 ? *(const unsigned*)(hsrc + ((size_t)sk0 << 6) + (l << 2)) : 0u;
        for (int i = 0; i < niter - 1; ++i) {
            int e2 = (i + 2) * 4 + g;
            bool ve2 = e2 < len;
            int sk2 = ve2 ? csr[off + e2] : 0;
            float a1 = ve1 ? as_[sk1] : -INFINITY;
            unsigned hv1 = ve1 ? *(const unsigned*)(hsrc + ((size_t)sk1 << 6) + (l << 2)) : 0u;
            float tt = a0 + adi;
            tt = (tt > 0.f) ? tt : LRELU_SLOPE * tt;
            float ex = __expf(tt);
            den += ex;
            f32x2 p0 = __builtin_amdgcn_cvt_pk_f32_fp8(hv0, false);
            f32x2 p1 = __builtin_amdgcn_cvt_pk_f32_fp8(hv0, true);
            acc0 = fmaf(ex, p0.x, acc0);
            acc1 = fmaf(ex, p0.y, acc1);
            acc2 = fmaf(ex, p1.x, acc2);
            acc3 = fmaf(ex, p1.y, acc3);
            a0 = a1; hv0 = hv1;
            sk1 = sk2; ve1 = ve2;
        }
        {
            float tt = a0 + adi;
            tt = (tt > 0.f) ? tt : LRELU_SLOPE * tt;
            float ex = __expf(tt);
            den += ex;
            f32x2 p0 = __builtin_amdgcn_cvt_pk_f32_fp8(hv0, false);
            f32x2 p1 = __builtin_amdgcn_cvt_pk_f32_fp8(hv0, true);
            acc0 = fmaf(ex, p0.x, acc0);
            acc1 = fmaf(ex, p0.y, acc1);
            acc2 = fmaf(ex, p1.x, acc2);
            acc3 = fmaf(ex, p1.y, acc3);
        }
        // reduce across the 4 groups (lanes differing in bits 4..5)
        acc0 += __shfl_xor(acc0, 16); acc0 += __shfl_xor(acc0, 32);
        acc1 += __shfl_xor(acc1, 16); acc1 += __shfl_xor(acc1, 32);
        acc2 += __shfl_xor(acc2, 16); acc2 += __shfl_xor(acc2, 32);
        acc3 += __shfl_xor(acc3, 16); acc3 += __shfl_xor(acc3, 32);
        den += __shfl_xor(den, 16);
        den += __shfl_xor(den, 32);
        float inv = 1.f / den;                 // full sum, counted once
        const float4 bv = *(const float4*)(bias + l * 4);
        v0 = fmaf(acc0, inv, bv.x);
        v1 = fmaf(acc1, inv, bv.y);
        v2 = fmaf(acc2, inv, bv.z);
        v3 = fmaf(acc3, inv, bv.w);
        if (mode == 1) {
            v0 = fmaxf(v0, 0.f); v1 = fmaxf(v1, 0.f);
            v2 = fmaxf(v2, 0.f); v3 = fmaxf(v3, 0.f);
            if (g == 0) {
                uint2 pk;
                pk.x = (unsigned)f2bf(v0) | ((unsigned)f2bf(v1) << 16);
                pk.y = (unsigned)f2bf(v2) | ((unsigned)f2bf(v3) << 16);
                *(uint2*)(out + (size_t)wave * NDIM + l * 4) = pk;
            }
        }
    }
    if (mode == 2) {
        if (g == 0) {
            psum[wid][l * 4 + 0] = v0;
            psum[wid][l * 4 + 1] = v1;
            psum[wid][l * 4 + 2] = v2;
            psum[wid][l * 4 + 3] = v3;
        }
        __syncthreads();
        if (threadIdx.x < NDIM) {
            float t = psum[0][threadIdx.x] + psum[1][threadIdx.x] +
                      psum[2][threadIdx.x] + psum[3][threadIdx.x];
            pool[(size_t)blockIdx.x * NDIM + threadIdx.x] = t;
        }
    }
}

// ---------------- final mean reduce over per-block partials ----------------
__global__ void mean_kernel(const float* __restrict__ pool, float* __restrict__ out,
                            int nb, float invn) {
    __shared__ float sm[4][NDIM];
    int lane = threadIdx.x & 63, wid = threadIdx.x >> 6;
    int row = blockIdx.x * 4 + wid;
    int stride = gridDim.x * 4;
    float s = 0.f;
    for (int i = row; i < nb; i += stride) s += pool[(long)i * NDIM + lane];
    sm[wid][lane] = s;
    __syncthreads();
    if (wid == 0) {
        float v = sm[0][lane] + sm[1][lane] + sm[2][lane] + sm[3][lane];
        atomicAdd(&out[lane], v * invn);
    }
}

extern "C" void kernel_launch(void* const* d_in, const int* in_sizes, int n_in,
                              void* d_out, int out_size, void* d_ws, size_t ws_size,
                              hipStream_t stream) {
    const float* x      = (const float*)d_in[0];
    const int*   eidx   = (const int*)d_in[1];
    const float* W1     = (const float*)d_in[2];
    const float* a_src1 = (const float*)d_in[3];
    const float* a_dst1 = (const float*)d_in[4];
    const float* b1     = (const float*)d_in[5];
    const float* W2     = (const float*)d_in[6];
    const float* a_src2 = (const float*)d_in[7];
    const float* a_dst2 = (const float*)d_in[8];
    const float* b2     = (const float*)d_in[9];
    float* out = (float*)d_out;

    const int N = in_sizes[0] / 20;      // 100000 (< 2^17, required by u32 part pack)
    const int E = in_sizes[1] / 2;       // 1000000
    const int* src = eidx;
    const int* dst = eidx + E;
    const int NB = (N + BNODES - 1) >> BSHIFT;   // 98

    // workspace layout (part[] aliased into h: dead before gemm1 writes h)
    char* ws = (char*)d_ws;
    unsigned char* h = (unsigned char*)ws;            // N*64 fp8 (6.4 MB)
    ushort* o   = (ushort*)(h + (size_t)N * NDIM);    // N*64 bf16 (12.8 MB)
    float* as_  = (float*)(o + (size_t)N * NDIM);     // N
    float* ad_  = as_ + N;                            // N
    int2*  offlen = (int2*)(ad_ + N);                 // N
    int*   csr  = (int*)(offlen + N);                 // NB*CCAP (5.2 MB)
    float* pool = (float*)(csr + (size_t)NB * CCAP);  // agg_blocks*64 (6.4 MB)
    int*   bcur = (int*)(pool + (size_t)((N + 3) / 4) * NDIM);  // NB
    unsigned* part = (unsigned*)ws;   // NB*ECAP u32 (4.8 MB, aliased with h)

    // build bucketed CSR (bcur zeroed by async memset; 0-based cursors)
    hipMemsetAsync(bcur, 0, (size_t)NB * sizeof(int), stream);
    part_kernel<<<(E + 4095) / 4096, 256, 0, stream>>>(src, dst, bcur, part, E, NB);
    csr_kernel<<<NB, 256, 0, stream>>>(bcur, part, csr, offlen, N);

    const int gemm_blocks = (N + 63) / 64;    // 1563 (64 nodes/block)
    const int agg_blocks  = (N + 3) / 4;      // 25000

    // layer 1
    gemm_kernel<20, 32, false><<<gemm_blocks, 256, 0, stream>>>(x, W1, a_src1, a_dst1, h, as_, ad_, N);
    agg_kernel<<<agg_blocks, 256, 0, stream>>>(offlen, csr, as_, ad_, h, b1, o, pool, N, 1);

    // layer 2
    gemm_kernel<64, 64, true><<<gemm_blocks, 256, 0, stream>>>(o, W2, a_src2, a_dst2, h, as_, ad_, N);
    agg_kernel<<<agg_blocks, 256, 0, stream>>>(offlen, csr, as_, ad_, h, b2, o, pool, N, 2);

    // final mean reduce
    hipMemsetAsync(d_out, 0, (size_t)out_size * sizeof(float), stream);
    mean_kernel<<<64, 256, 0, stream>>>(pool, out, agg_blocks, 1.0f / (float)N);
}

// Round 12
// 239.146 us; speedup vs baseline: 1.0785x; 1.0785x over previous
//
#include <hip/hip_runtime.h>
#include <math.h>

#define NDIM 64
#define LRELU_SLOPE 0.2f
#define BSHIFT 8               // 256 nodes per bucket (r11's 1024 regressed: LDS-atomic contention)
#define BNODES 256
#define ECAP 3584              // edge capacity per bucket (mean 2558, ~20 sigma headroom)
#define CCAP (ECAP + BNODES)   // csr capacity per bucket (edges + self loops)

typedef float f32x2 __attribute__((ext_vector_type(2)));

__device__ __forceinline__ ushort f2bf(float f) {
    unsigned u = __float_as_uint(f);
    unsigned r = (u + 0x7fffu + ((u >> 16) & 1u)) >> 16;   // RTNE
    return (ushort)r;
}
__device__ __forceinline__ float bflo(unsigned u) { return __uint_as_float(u << 16); }
__device__ __forceinline__ float bfhi(unsigned u) { return __uint_as_float(u & 0xffff0000u); }

// ---------------- partition edges into dst-buckets (packed u32 dl<<17|s) ---
// Requires N < 131072 (s fits 17 bits); dl < 256 (8 bits). bcur 0-based
// (zeroed by memset); slot = b*ECAP + reserved + local.
__global__ __launch_bounds__(256) void part_kernel(
    const int* __restrict__ src, const int* __restrict__ dst,
    int* __restrict__ bcur, unsigned* __restrict__ part,
    int E, int nb) {
    __shared__ int hist[512];
    __shared__ int base[512];
    int t = threadIdx.x;
    for (int i = t; i < nb; i += 256) hist[i] = 0;
    __syncthreads();
    int chunk = blockIdx.x * 4096;
    int s[16], d[16];
#pragma unroll
    for (int j = 0; j < 4; ++j) {
        int idx = chunk + j * 1024 + t * 4;
        if (idx + 3 < E) {
            int4 sv = *(const int4*)(src + idx);
            int4 dv = *(const int4*)(dst + idx);
            s[j*4+0]=sv.x; s[j*4+1]=sv.y; s[j*4+2]=sv.z; s[j*4+3]=sv.w;
            d[j*4+0]=dv.x; d[j*4+1]=dv.y; d[j*4+2]=dv.z; d[j*4+3]=dv.w;
        } else {
#pragma unroll
            for (int q = 0; q < 4; ++q) {
                int i2 = idx + q;
                if (i2 < E) { s[j*4+q] = src[i2]; d[j*4+q] = dst[i2]; }
                else        { s[j*4+q] = 0;       d[j*4+q] = -1; }
            }
        }
    }
#pragma unroll
    for (int j = 0; j < 16; ++j)
        if (d[j] >= 0) atomicAdd(&hist[d[j] >> BSHIFT], 1);
    __syncthreads();
    for (int i = t; i < nb; i += 256) {
        int c = hist[i];
        base[i] = c ? atomicAdd(&bcur[i], c) : 0;
        hist[i] = 0;          // reuse as running cursor
    }
    __syncthreads();
#pragma unroll
    for (int j = 0; j < 16; ++j) {
        if (d[j] >= 0) {
            int b = d[j] >> BSHIFT;
            int pos = base[b] + atomicAdd(&hist[b], 1);
            if (pos > ECAP - 1) pos = ECAP - 1;   // never fires statistically
            part[(size_t)b * ECAP + pos] =
                ((unsigned)(d[j] & (BNODES - 1)) << 17) | (unsigned)s[j];
        }
    }
}

// ---------------- per-bucket CSR build (LDS hist + scan + LDS-cursor scatter)
__global__ __launch_bounds__(256) void csr_kernel(
    const int* __restrict__ bcur, const unsigned* __restrict__ part,
    int* __restrict__ csr, int2* __restrict__ offlen, int N) {
    __shared__ int hist[256];
    __shared__ int sc[256];
    int b = blockIdx.x, t = threadIdx.x;
    int nodeBase = b << BSHIFT;
    int nNodes = min(BNODES, N - nodeBase);
    int count = min(bcur[b], ECAP);
    hist[t] = (t < nNodes) ? 1 : 0;      // self-loop
    __syncthreads();
    const unsigned* slice = part + (size_t)b * ECAP;
    for (int i = t; i < count; i += 256) {
        int dl = (int)(slice[i] >> 17);
        atomicAdd(&hist[dl], 1);
    }
    __syncthreads();
    int cnt = hist[t];
    sc[t] = cnt;
    __syncthreads();
    for (int o = 1; o < 256; o <<= 1) {
        int v = sc[t];
        int u = (t >= o) ? sc[t - o] : 0;
        __syncthreads();
        sc[t] = v + u;
        __syncthreads();
    }
    int excl = sc[t] - cnt;              // exclusive scan
    int boff = b * CCAP;
    if (t < nNodes) {
        offlen[nodeBase + t] = make_int2(boff + excl, cnt);
        csr[boff + excl] = nodeBase + t; // self loop first
    }
    hist[t] = excl + 1;                  // running local cursor
    __syncthreads();
    for (int i = t; i < count; i += 256) {
        unsigned e = slice[i];
        int dl = (int)(e >> 17);
        int pos = boff + atomicAdd(&hist[dl], 1);
        csr[pos] = (int)(e & 0x1ffffu);
    }
}

// ---------------- j-split GEMM: 64 nodes/block, wave wid owns 16 dims ------
// h output is fp8-e4m3 (HW cvt), 16 u32-quads per node via pitch-17 LDS
// transpose. as/ad stay fp32.
template<int K, int KS, bool BF16IN>
__global__ __launch_bounds__(256) void gemm_kernel(
    const void* __restrict__ Xv, const float* __restrict__ W,
    const float* __restrict__ asrc, const float* __restrict__ adst,
    unsigned char* __restrict__ h, float* __restrict__ as_, float* __restrict__ ad_, int N) {
    __shared__ float xs[64 * KS];          // swizzled input tile
    __shared__ unsigned hsq[64 * 17];      // fp8 quad transpose buffer (4.4 KB)
    __shared__ float ps[2][4][64];         // as/ad partials
    int t = threadIdx.x;
    int base = blockIdx.x * 64;
    if (BF16IN) {
        const unsigned* X = (const unsigned*)Xv;   // K/2 uints per row
        for (int i = t; i < 64 * (K / 2); i += 256) {
            int nl = i / (K / 2), p = i - nl * (K / 2);
            int k = p * 2;
            int node = base + nl;
            unsigned u = (node < N) ? X[(size_t)node * (K / 2) + p] : 0u;
            xs[nl * KS + ((k + nl) & (KS - 1))] = bflo(u);
            xs[nl * KS + ((k + 1 + nl) & (KS - 1))] = bfhi(u);
        }
    } else {
        const float* X = (const float*)Xv;
        for (int i = t; i < 64 * KS; i += 256) {
            int nl = i / KS, k = i - nl * KS;
            int node = base + nl;
            float v = (k < K && node < N) ? X[(size_t)node * K + k] : 0.f;
            xs[nl * KS + ((k + nl) & (KS - 1))] = v;
        }
    }
    __syncthreads();
    int wid = __builtin_amdgcn_readfirstlane(t >> 6);   // force scalar
    int lane = t & 63;
    int node = base + lane;
    float acc[16];
#pragma unroll
    for (int j = 0; j < 16; ++j) acc[j] = 0.f;
    const float* Wg = W + wid * 16;
    const float* xrow = xs + lane * KS;
#pragma unroll 4
    for (int k = 0; k < K; ++k) {
        float xk = xrow[(k + lane) & (KS - 1)];
#pragma unroll
        for (int j = 0; j < 16; ++j)
            acc[j] = fmaf(xk, Wg[k * 64 + j], acc[j]);
    }
    // as/ad partials over this wave's 16 dims
    float s = 0.f, d = 0.f;
#pragma unroll
    for (int j = 0; j < 16; ++j) {
        s = fmaf(acc[j], asrc[wid * 16 + j], s);
        d = fmaf(acc[j], adst[wid * 16 + j], d);
    }
    ps[0][wid][lane] = s;
    ps[1][wid][lane] = d;
    // pack 4 dims -> 1 fp8 quad (u32), write swizzled
#pragma unroll
    for (int j = 0; j < 16; j += 4) {
        int q = (wid * 16 + j) >> 2;            // quad index 0..15
        int sp = (q + lane) & 15;
        int u = __builtin_amdgcn_cvt_pk_fp8_f32(acc[j], acc[j + 1], 0, false);
        u = __builtin_amdgcn_cvt_pk_fp8_f32(acc[j + 2], acc[j + 3], u, true);
        hsq[lane * 17 + sp] = (unsigned)u;
    }
    __syncthreads();
    if (wid == 0) {
        float s4 = ps[0][0][lane] + ps[0][1][lane] + ps[0][2][lane] + ps[0][3][lane];
        float d4 = ps[1][0][lane] + ps[1][1][lane] + ps[1][2][lane] + ps[1][3][lane];
        if (node < N) { as_[node] = s4; ad_[node] = d4; }
    }
    // coalesced fp8x4 store of the 64x64 tile (16 u32 per node)
    unsigned* hout = (unsigned*)h;
    for (int pass = 0; pass < 4; ++pass) {
        int row = pass * 16 + (t >> 4);
        int q = t & 15;
        int sp = (q + row) & 15;
        unsigned v = hsq[row * 17 + sp];
        int n2 = base + row;
        if (n2 < N) hout[(size_t)n2 * 16 + q] = v;
    }
}

// ---------------- fused softmax + weighted-gather aggregation --------------
// Wave per node; 8 groups of 8 lanes; group g handles edge i*8+g; lane loads
// uint2 = 8 fp8 dims of h[src] (row = 64 B = one cache line). Softmax fused:
// ex=exp(lrelu(as[src]+ad[dst])), no max-subtraction (bounded logits).
// Masked edges: -INF sentinel -> ex=0. After shfl_xor(8/16/32) reduction den
// holds the full sum ONCE -> inv = 1/den.
// r11 lesson: keep 8 B/lane loads — 4-group/4 B variant issued 1.5x VMEM and
// regressed 25 us despite a cheaper epilogue.
__global__ __launch_bounds__(256) void agg_kernel(
    const int2* __restrict__ offlen, const int* __restrict__ csr,
    const float* __restrict__ as_, const float* __restrict__ ad_,
    const unsigned char* __restrict__ hsrc, const float* __restrict__ bias,
    ushort* __restrict__ out, float* __restrict__ pool, int n, int mode) {
    __shared__ float psum[4][NDIM];
    int wid = threadIdx.x >> 6, lane = threadIdx.x & 63;
    int g = lane >> 3, l = lane & 7;
    int wave = blockIdx.x * 4 + wid;
    float v[8];
#pragma unroll
    for (int j = 0; j < 8; ++j) v[j] = 0.f;
    if (wave < n) {
        int2 ol = offlen[wave];
        int off = ol.x, len = ol.y;
        float adi = ad_[wave];
        float acc[8];
#pragma unroll
        for (int j = 0; j < 8; ++j) acc[j] = 0.f;
        float den = 0.f;
        int niter = (len + 7) >> 3;
        int e0 = g, e1 = 8 + g;
        bool ve0 = e0 < len, ve1 = e1 < len;
        int sk0 = ve0 ? csr[off + e0] : 0;
        int sk1 = ve1 ? csr[off + e1] : 0;
        float a0 = ve0 ? as_[sk0] : -INFINITY;
        uint2 hv0 = make_uint2(0, 0);
        if (ve0) hv0 = *(const uint2*)(hsrc + ((size_t)sk0 << 6) + (l << 3));
        for (int i = 0; i < niter - 1; ++i) {
            int e2 = (i + 2) * 8 + g;
            bool ve2 = e2 < len;
            int sk2 = ve2 ? csr[off + e2] : 0;
            float a1 = ve1 ? as_[sk1] : -INFINITY;
            uint2 hv1 = make_uint2(0, 0);
            if (ve1) hv1 = *(const uint2*)(hsrc + ((size_t)sk1 << 6) + (l << 3));
            float tt = a0 + adi;
            tt = (tt > 0.f) ? tt : LRELU_SLOPE * tt;
            float ex = __expf(tt);
            den += ex;
            f32x2 p0 = __builtin_amdgcn_cvt_pk_f32_fp8(hv0.x, false);
            f32x2 p1 = __builtin_amdgcn_cvt_pk_f32_fp8(hv0.x, true);
            f32x2 p2 = __builtin_amdgcn_cvt_pk_f32_fp8(hv0.y, false);
            f32x2 p3 = __builtin_amdgcn_cvt_pk_f32_fp8(hv0.y, true);
            acc[0] = fmaf(ex, p0.x, acc[0]);
            acc[1] = fmaf(ex, p0.y, acc[1]);
            acc[2] = fmaf(ex, p1.x, acc[2]);
            acc[3] = fmaf(ex, p1.y, acc[3]);
            acc[4] = fmaf(ex, p2.x, acc[4]);
            acc[5] = fmaf(ex, p2.y, acc[5]);
            acc[6] = fmaf(ex, p3.x, acc[6]);
            acc[7] = fmaf(ex, p3.y, acc[7]);
            a0 = a1; hv0 = hv1;
            sk1 = sk2; ve1 = ve2;
        }
        {
            float tt = a0 + adi;
            tt = (tt > 0.f) ? tt : LRELU_SLOPE * tt;
            float ex = __expf(tt);
            den += ex;
            f32x2 p0 = __builtin_amdgcn_cvt_pk_f32_fp8(hv0.x, false);
            f32x2 p1 = __builtin_amdgcn_cvt_pk_f32_fp8(hv0.x, true);
            f32x2 p2 = __builtin_amdgcn_cvt_pk_f32_fp8(hv0.y, false);
            f32x2 p3 = __builtin_amdgcn_cvt_pk_f32_fp8(hv0.y, true);
            acc[0] = fmaf(ex, p0.x, acc[0]);
            acc[1] = fmaf(ex, p0.y, acc[1]);
            acc[2] = fmaf(ex, p1.x, acc[2]);
            acc[3] = fmaf(ex, p1.y, acc[3]);
            acc[4] = fmaf(ex, p2.x, acc[4]);
            acc[5] = fmaf(ex, p2.y, acc[5]);
            acc[6] = fmaf(ex, p3.x, acc[6]);
            acc[7] = fmaf(ex, p3.y, acc[7]);
        }
        // reduce across the 8 groups (lanes differing in bits 3..5)
#pragma unroll
        for (int j = 0; j < 8; ++j) {
            acc[j] += __shfl_xor(acc[j], 8);
            acc[j] += __shfl_xor(acc[j], 16);
            acc[j] += __shfl_xor(acc[j], 32);
        }
        den += __shfl_xor(den, 8);
        den += __shfl_xor(den, 16);
        den += __shfl_xor(den, 32);
        float inv = 1.f / den;                 // full sum, counted once
        const float4 bv0 = *(const float4*)(bias + l * 8);
        const float4 bv1 = *(const float4*)(bias + l * 8 + 4);
        v[0] = fmaf(acc[0], inv, bv0.x);
        v[1] = fmaf(acc[1], inv, bv0.y);
        v[2] = fmaf(acc[2], inv, bv0.z);
        v[3] = fmaf(acc[3], inv, bv0.w);
        v[4] = fmaf(acc[4], inv, bv1.x);
        v[5] = fmaf(acc[5], inv, bv1.y);
        v[6] = fmaf(acc[6], inv, bv1.z);
        v[7] = fmaf(acc[7], inv, bv1.w);
        if (mode == 1) {
#pragma unroll
            for (int j = 0; j < 8; ++j) v[j] = fmaxf(v[j], 0.f);
            if (g == 0) {
                uint4 pk;
                pk.x = (unsigned)f2bf(v[0]) | ((unsigned)f2bf(v[1]) << 16);
                pk.y = (unsigned)f2bf(v[2]) | ((unsigned)f2bf(v[3]) << 16);
                pk.z = (unsigned)f2bf(v[4]) | ((unsigned)f2bf(v[5]) << 16);
                pk.w = (unsigned)f2bf(v[6]) | ((unsigned)f2bf(v[7]) << 16);
                *(uint4*)(out + (size_t)wave * NDIM + l * 8) = pk;
            }
        }
    }
    if (mode == 2) {
        if (g == 0) {
#pragma unroll
            for (int j = 0; j < 8; ++j) psum[wid][l * 8 + j] = v[j];
        }
        __syncthreads();
        if (threadIdx.x < NDIM) {
            float t = psum[0][threadIdx.x] + psum[1][threadIdx.x] +
                      psum[2][threadIdx.x] + psum[3][threadIdx.x];
            pool[(size_t)blockIdx.x * NDIM + threadIdx.x] = t;
        }
    }
}

// ---------------- final mean reduce over per-block partials ----------------
__global__ void mean_kernel(const float* __restrict__ pool, float* __restrict__ out,
                            int nb, float invn) {
    __shared__ float sm[4][NDIM];
    int lane = threadIdx.x & 63, wid = threadIdx.x >> 6;
    int row = blockIdx.x * 4 + wid;
    int stride = gridDim.x * 4;
    float s = 0.f;
    for (int i = row; i < nb; i += stride) s += pool[(long)i * NDIM + lane];
    sm[wid][lane] = s;
    __syncthreads();
    if (wid == 0) {
        float v = sm[0][lane] + sm[1][lane] + sm[2][lane] + sm[3][lane];
        atomicAdd(&out[lane], v * invn);
    }
}

extern "C" void kernel_launch(void* const* d_in, const int* in_sizes, int n_in,
                              void* d_out, int out_size, void* d_ws, size_t ws_size,
                              hipStream_t stream) {
    const float* x      = (const float*)d_in[0];
    const int*   eidx   = (const int*)d_in[1];
    const float* W1     = (const float*)d_in[2];
    const float* a_src1 = (const float*)d_in[3];
    const float* a_dst1 = (const float*)d_in[4];
    const float* b1     = (const float*)d_in[5];
    const float* W2     = (const float*)d_in[6];
    const float* a_src2 = (const float*)d_in[7];
    const float* a_dst2 = (const float*)d_in[8];
    const float* b2     = (const float*)d_in[9];
    float* out = (float*)d_out;

    const int N = in_sizes[0] / 20;      // 100000 (< 2^17, required by u32 part pack)
    const int E = in_sizes[1] / 2;       // 1000000
    const int* src = eidx;
    const int* dst = eidx + E;
    const int NB = (N + BNODES - 1) >> BSHIFT;   // 391

    // workspace layout (part[] aliased into h: dead before gemm1 writes h)
    char* ws = (char*)d_ws;
    unsigned char* h = (unsigned char*)ws;            // N*64 fp8 (6.4 MB)
    ushort* o   = (ushort*)(h + (size_t)N * NDIM);    // N*64 bf16 (12.8 MB)
    float* as_  = (float*)(o + (size_t)N * NDIM);     // N
    float* ad_  = as_ + N;                            // N
    int2*  offlen = (int2*)(ad_ + N);                 // N
    int*   csr  = (int*)(offlen + N);                 // NB*CCAP
    float* pool = (float*)(csr + (size_t)NB * CCAP);  // agg_blocks*64
    int*   bcur = (int*)(pool + (size_t)((N + 3) / 4) * NDIM);  // NB
    unsigned* part = (unsigned*)ws;   // NB*ECAP u32 (5.6 MB, aliased with h)

    // build bucketed CSR (bcur zeroed by async memset; 0-based cursors)
    hipMemsetAsync(bcur, 0, (size_t)NB * sizeof(int), stream);
    part_kernel<<<(E + 4095) / 4096, 256, 0, stream>>>(src, dst, bcur, part, E, NB);
    csr_kernel<<<NB, 256, 0, stream>>>(bcur, part, csr, offlen, N);

    const int gemm_blocks = (N + 63) / 64;    // 1563 (64 nodes/block)
    const int agg_blocks  = (N + 3) / 4;      // 25000

    // layer 1
    gemm_kernel<20, 32, false><<<gemm_blocks, 256, 0, stream>>>(x, W1, a_src1, a_dst1, h, as_, ad_, N);
    agg_kernel<<<agg_blocks, 256, 0, stream>>>(offlen, csr, as_, ad_, h, b1, o, pool, N, 1);

    // layer 2
    gemm_kernel<64, 64, true><<<gemm_blocks, 256, 0, stream>>>(o, W2, a_src2, a_dst2, h, as_, ad_, N);
    agg_kernel<<<agg_blocks, 256, 0, stream>>>(offlen, csr, as_, ad_, h, b2, o, pool, N, 2);

    // final mean reduce
    hipMemsetAsync(d_out, 0, (size_t)out_size * sizeof(float), stream);
    mean_kernel<<<64, 256, 0, stream>>>(pool, out, agg_blocks, 1.0f / (float)N);
}

// Round 13
// 233.766 us; speedup vs baseline: 1.1033x; 1.0230x over previous
//
#include <hip/hip_runtime.h>
#include <math.h>

#define NDIM 64
#define LRELU_SLOPE 0.2f
#define BSHIFT 8               // 256 nodes per bucket (r11's 1024 regressed: LDS-atomic contention)
#define BNODES 256
#define ECAP 3584              // edge capacity per bucket (mean 2558, ~20 sigma headroom)
#define CCAP (ECAP + BNODES)   // csr capacity per bucket (edges + self loops)

typedef float f32x2 __attribute__((ext_vector_type(2)));

__device__ __forceinline__ ushort f2bf(float f) {
    unsigned u = __float_as_uint(f);
    unsigned r = (u + 0x7fffu + ((u >> 16) & 1u)) >> 16;   // RTNE
    return (ushort)r;
}
__device__ __forceinline__ float bflo(unsigned u) { return __uint_as_float(u << 16); }
__device__ __forceinline__ float bfhi(unsigned u) { return __uint_as_float(u & 0xffff0000u); }

// ---------------- fused: edge partition (blocks < PB) + GEMM1 (rest) -------
// The two workloads are independent; fusing fills part's latency stalls
// (16 scattered stores/thread at <=1 block/CU) with gemm1's VALU work.
// part is NOT aliased with h here (gemm1 writes h concurrently).
__global__ __launch_bounds__(256) void pg1_kernel(
    const int* __restrict__ src, const int* __restrict__ dst,
    int* __restrict__ bcur, unsigned* __restrict__ part, int E, int nb, int PB,
    const float* __restrict__ X, const float* __restrict__ W,
    const float* __restrict__ asrc, const float* __restrict__ adst,
    unsigned char* __restrict__ h, float* __restrict__ as_, float* __restrict__ ad_,
    int N) {
    __shared__ float smem[3648];           // 14.6 KB overlay for both branches
    int t = threadIdx.x;
    if (blockIdx.x < PB) {
        // ---- partition branch (packed u32 dl<<17|s; needs N < 2^17) ----
        int* hist = (int*)smem;            // 512 ints
        int* base = hist + 512;            // 512 ints
        for (int i = t; i < nb; i += 256) hist[i] = 0;
        __syncthreads();
        int chunk = blockIdx.x * 4096;
        int s[16], d[16];
#pragma unroll
        for (int j = 0; j < 4; ++j) {
            int idx = chunk + j * 1024 + t * 4;
            if (idx + 3 < E) {
                int4 sv = *(const int4*)(src + idx);
                int4 dv = *(const int4*)(dst + idx);
                s[j*4+0]=sv.x; s[j*4+1]=sv.y; s[j*4+2]=sv.z; s[j*4+3]=sv.w;
                d[j*4+0]=dv.x; d[j*4+1]=dv.y; d[j*4+2]=dv.z; d[j*4+3]=dv.w;
            } else {
#pragma unroll
                for (int q = 0; q < 4; ++q) {
                    int i2 = idx + q;
                    if (i2 < E) { s[j*4+q] = src[i2]; d[j*4+q] = dst[i2]; }
                    else        { s[j*4+q] = 0;       d[j*4+q] = -1; }
                }
            }
        }
#pragma unroll
        for (int j = 0; j < 16; ++j)
            if (d[j] >= 0) atomicAdd(&hist[d[j] >> BSHIFT], 1);
        __syncthreads();
        for (int i = t; i < nb; i += 256) {
            int c = hist[i];
            base[i] = c ? atomicAdd(&bcur[i], c) : 0;
            hist[i] = 0;          // reuse as running cursor
        }
        __syncthreads();
#pragma unroll
        for (int j = 0; j < 16; ++j) {
            if (d[j] >= 0) {
                int b = d[j] >> BSHIFT;
                int pos = base[b] + atomicAdd(&hist[b], 1);
                if (pos > ECAP - 1) pos = ECAP - 1;   // never fires statistically
                part[(size_t)b * ECAP + pos] =
                    ((unsigned)(d[j] & (BNODES - 1)) << 17) | (unsigned)s[j];
            }
        }
    } else {
        // ---- GEMM1 branch: h = x @ W1 (K=20), 64 nodes/block ----
        const int K = 20, KS = 32;
        float* xs = smem;                          // 64*32 = 2048 floats
        unsigned* hsq = (unsigned*)(smem + 2048);  // 64*17 = 1088 u32
        float* ps = smem + 3136;                   // 2*4*64 = 512 floats
        int nbase = (int)(blockIdx.x - PB) * 64;
        for (int i = t; i < 64 * KS; i += 256) {
            int nl = i / KS, k = i - nl * KS;
            int node = nbase + nl;
            float v = (k < K && node < N) ? X[(size_t)node * K + k] : 0.f;
            xs[nl * KS + ((k + nl) & (KS - 1))] = v;
        }
        __syncthreads();
        int wid = __builtin_amdgcn_readfirstlane(t >> 6);
        int lane = t & 63;
        int node = nbase + lane;
        float acc[16];
#pragma unroll
        for (int j = 0; j < 16; ++j) acc[j] = 0.f;
        const float* Wg = W + wid * 16;
        const float* xrow = xs + lane * KS;
#pragma unroll 4
        for (int k = 0; k < K; ++k) {
            float xk = xrow[(k + lane) & (KS - 1)];
#pragma unroll
            for (int j = 0; j < 16; ++j)
                acc[j] = fmaf(xk, Wg[k * 64 + j], acc[j]);
        }
        float sx = 0.f, dx = 0.f;
#pragma unroll
        for (int j = 0; j < 16; ++j) {
            sx = fmaf(acc[j], asrc[wid * 16 + j], sx);
            dx = fmaf(acc[j], adst[wid * 16 + j], dx);
        }
        ps[0 * 256 + wid * 64 + lane] = sx;
        ps[1 * 256 + wid * 64 + lane] = dx;
#pragma unroll
        for (int j = 0; j < 16; j += 4) {
            int q = (wid * 16 + j) >> 2;
            int sp = (q + lane) & 15;
            int u = __builtin_amdgcn_cvt_pk_fp8_f32(acc[j], acc[j + 1], 0, false);
            u = __builtin_amdgcn_cvt_pk_fp8_f32(acc[j + 2], acc[j + 3], u, true);
            hsq[lane * 17 + sp] = (unsigned)u;
        }
        __syncthreads();
        if (wid == 0) {
            float s4 = ps[0*256 + 0*64 + lane] + ps[0*256 + 1*64 + lane] +
                       ps[0*256 + 2*64 + lane] + ps[0*256 + 3*64 + lane];
            float d4 = ps[1*256 + 0*64 + lane] + ps[1*256 + 1*64 + lane] +
                       ps[1*256 + 2*64 + lane] + ps[1*256 + 3*64 + lane];
            if (node < N) { as_[node] = s4; ad_[node] = d4; }
        }
        unsigned* hout = (unsigned*)h;
        for (int pass = 0; pass < 4; ++pass) {
            int row = pass * 16 + (t >> 4);
            int q = t & 15;
            int sp = (q + row) & 15;
            unsigned v = hsq[row * 17 + sp];
            int n2 = nbase + row;
            if (n2 < N) hout[(size_t)n2 * 16 + q] = v;
        }
    }
}

// ---------------- per-bucket CSR build (LDS hist + scan + LDS-cursor scatter)
__global__ __launch_bounds__(256) void csr_kernel(
    const int* __restrict__ bcur, const unsigned* __restrict__ part,
    int* __restrict__ csr, int2* __restrict__ offlen, int N) {
    __shared__ int hist[256];
    __shared__ int sc[256];
    int b = blockIdx.x, t = threadIdx.x;
    int nodeBase = b << BSHIFT;
    int nNodes = min(BNODES, N - nodeBase);
    int count = min(bcur[b], ECAP);
    hist[t] = (t < nNodes) ? 1 : 0;      // self-loop
    __syncthreads();
    const unsigned* slice = part + (size_t)b * ECAP;
    for (int i = t; i < count; i += 256) {
        int dl = (int)(slice[i] >> 17);
        atomicAdd(&hist[dl], 1);
    }
    __syncthreads();
    int cnt = hist[t];
    sc[t] = cnt;
    __syncthreads();
    for (int o = 1; o < 256; o <<= 1) {
        int v = sc[t];
        int u = (t >= o) ? sc[t - o] : 0;
        __syncthreads();
        sc[t] = v + u;
        __syncthreads();
    }
    int excl = sc[t] - cnt;              // exclusive scan
    int boff = b * CCAP;
    if (t < nNodes) {
        offlen[nodeBase + t] = make_int2(boff + excl, cnt);
        csr[boff + excl] = nodeBase + t; // self loop first
    }
    hist[t] = excl + 1;                  // running local cursor
    __syncthreads();
    for (int i = t; i < count; i += 256) {
        unsigned e = slice[i];
        int dl = (int)(e >> 17);
        int pos = boff + atomicAdd(&hist[dl], 1);
        csr[pos] = (int)(e & 0x1ffffu);
    }
}

// ---------------- j-split GEMM2: 64 nodes/block, wave wid owns 16 dims -----
// bf16 input rows; fp8-e4m3 output via pitch-17 LDS transpose.
template<int K, int KS>
__global__ __launch_bounds__(256) void gemm_kernel(
    const void* __restrict__ Xv, const float* __restrict__ W,
    const float* __restrict__ asrc, const float* __restrict__ adst,
    unsigned char* __restrict__ h, float* __restrict__ as_, float* __restrict__ ad_, int N) {
    __shared__ float xs[64 * KS];          // swizzled input tile
    __shared__ unsigned hsq[64 * 17];      // fp8 quad transpose buffer (4.4 KB)
    __shared__ float ps[2][4][64];         // as/ad partials
    int t = threadIdx.x;
    int base = blockIdx.x * 64;
    const unsigned* X = (const unsigned*)Xv;   // K/2 uints per row (bf16x2)
    for (int i = t; i < 64 * (K / 2); i += 256) {
        int nl = i / (K / 2), p = i - nl * (K / 2);
        int k = p * 2;
        int node = base + nl;
        unsigned u = (node < N) ? X[(size_t)node * (K / 2) + p] : 0u;
        xs[nl * KS + ((k + nl) & (KS - 1))] = bflo(u);
        xs[nl * KS + ((k + 1 + nl) & (KS - 1))] = bfhi(u);
    }
    __syncthreads();
    int wid = __builtin_amdgcn_readfirstlane(t >> 6);   // force scalar
    int lane = t & 63;
    int node = base + lane;
    float acc[16];
#pragma unroll
    for (int j = 0; j < 16; ++j) acc[j] = 0.f;
    const float* Wg = W + wid * 16;
    const float* xrow = xs + lane * KS;
#pragma unroll 4
    for (int k = 0; k < K; ++k) {
        float xk = xrow[(k + lane) & (KS - 1)];
#pragma unroll
        for (int j = 0; j < 16; ++j)
            acc[j] = fmaf(xk, Wg[k * 64 + j], acc[j]);
    }
    float s = 0.f, d = 0.f;
#pragma unroll
    for (int j = 0; j < 16; ++j) {
        s = fmaf(acc[j], asrc[wid * 16 + j], s);
        d = fmaf(acc[j], adst[wid * 16 + j], d);
    }
    ps[0][wid][lane] = s;
    ps[1][wid][lane] = d;
#pragma unroll
    for (int j = 0; j < 16; j += 4) {
        int q = (wid * 16 + j) >> 2;            // quad index 0..15
        int sp = (q + lane) & 15;
        int u = __builtin_amdgcn_cvt_pk_fp8_f32(acc[j], acc[j + 1], 0, false);
        u = __builtin_amdgcn_cvt_pk_fp8_f32(acc[j + 2], acc[j + 3], u, true);
        hsq[lane * 17 + sp] = (unsigned)u;
    }
    __syncthreads();
    if (wid == 0) {
        float s4 = ps[0][0][lane] + ps[0][1][lane] + ps[0][2][lane] + ps[0][3][lane];
        float d4 = ps[1][0][lane] + ps[1][1][lane] + ps[1][2][lane] + ps[1][3][lane];
        if (node < N) { as_[node] = s4; ad_[node] = d4; }
    }
    unsigned* hout = (unsigned*)h;
    for (int pass = 0; pass < 4; ++pass) {
        int row = pass * 16 + (t >> 4);
        int q = t & 15;
        int sp = (q + row) & 15;
        unsigned v = hsq[row * 17 + sp];
        int n2 = base + row;
        if (n2 < N) hout[(size_t)n2 * 16 + q] = v;
    }
}

// ---------------- fused softmax + weighted-gather aggregation --------------
// Wave per node; 8 groups of 8 lanes; group g handles edge i*8+g; lane loads
// uint2 = 8 fp8 dims of h[src] (row = 64 B = one cache line). Softmax fused:
// ex=exp(lrelu(as[src]+ad[dst])), no max-subtraction (bounded logits).
// Masked edges: -INF sentinel -> ex=0. After shfl_xor(8/16/32) reduction den
// holds the full sum ONCE -> inv = 1/den.
// r11 lesson: keep 8 B/lane loads — 4-group/4 B variant issued 1.5x VMEM and
// regressed 25 us despite a cheaper epilogue.
__global__ __launch_bounds__(256) void agg_kernel(
    const int2* __restrict__ offlen, const int* __restrict__ csr,
    const float* __restrict__ as_, const float* __restrict__ ad_,
    const unsigned char* __restrict__ hsrc, const float* __restrict__ bias,
    ushort* __restrict__ out, float* __restrict__ pool, int n, int mode) {
    __shared__ float psum[4][NDIM];
    int wid = threadIdx.x >> 6, lane = threadIdx.x & 63;
    int g = lane >> 3, l = lane & 7;
    int wave = blockIdx.x * 4 + wid;
    float v[8];
#pragma unroll
    for (int j = 0; j < 8; ++j) v[j] = 0.f;
    if (wave < n) {
        int2 ol = offlen[wave];
        int off = ol.x, len = ol.y;
        float adi = ad_[wave];
        float acc[8];
#pragma unroll
        for (int j = 0; j < 8; ++j) acc[j] = 0.f;
        float den = 0.f;
        int niter = (len + 7) >> 3;
        int e0 = g, e1 = 8 + g;
        bool ve0 = e0 < len, ve1 = e1 < len;
        int sk0 = ve0 ? csr[off + e0] : 0;
        int sk1 = ve1 ? csr[off + e1] : 0;
        float a0 = ve0 ? as_[sk0] : -INFINITY;
        uint2 hv0 = make_uint2(0, 0);
        if (ve0) hv0 = *(const uint2*)(hsrc + ((size_t)sk0 << 6) + (l << 3));
        for (int i = 0; i < niter - 1; ++i) {
            int e2 = (i + 2) * 8 + g;
            bool ve2 = e2 < len;
            int sk2 = ve2 ? csr[off + e2] : 0;
            float a1 = ve1 ? as_[sk1] : -INFINITY;
            uint2 hv1 = make_uint2(0, 0);
            if (ve1) hv1 = *(const uint2*)(hsrc + ((size_t)sk1 << 6) + (l << 3));
            float tt = a0 + adi;
            tt = (tt > 0.f) ? tt : LRELU_SLOPE * tt;
            float ex = __expf(tt);
            den += ex;
            f32x2 p0 = __builtin_amdgcn_cvt_pk_f32_fp8(hv0.x, false);
            f32x2 p1 = __builtin_amdgcn_cvt_pk_f32_fp8(hv0.x, true);
            f32x2 p2 = __builtin_amdgcn_cvt_pk_f32_fp8(hv0.y, false);
            f32x2 p3 = __builtin_amdgcn_cvt_pk_f32_fp8(hv0.y, true);
            acc[0] = fmaf(ex, p0.x, acc[0]);
            acc[1] = fmaf(ex, p0.y, acc[1]);
            acc[2] = fmaf(ex, p1.x, acc[2]);
            acc[3] = fmaf(ex, p1.y, acc[3]);
            acc[4] = fmaf(ex, p2.x, acc[4]);
            acc[5] = fmaf(ex, p2.y, acc[5]);
            acc[6] = fmaf(ex, p3.x, acc[6]);
            acc[7] = fmaf(ex, p3.y, acc[7]);
            a0 = a1; hv0 = hv1;
            sk1 = sk2; ve1 = ve2;
        }
        {
            float tt = a0 + adi;
            tt = (tt > 0.f) ? tt : LRELU_SLOPE * tt;
            float ex = __expf(tt);
            den += ex;
            f32x2 p0 = __builtin_amdgcn_cvt_pk_f32_fp8(hv0.x, false);
            f32x2 p1 = __builtin_amdgcn_cvt_pk_f32_fp8(hv0.x, true);
            f32x2 p2 = __builtin_amdgcn_cvt_pk_f32_fp8(hv0.y, false);
            f32x2 p3 = __builtin_amdgcn_cvt_pk_f32_fp8(hv0.y, true);
            acc[0] = fmaf(ex, p0.x, acc[0]);
            acc[1] = fmaf(ex, p0.y, acc[1]);
            acc[2] = fmaf(ex, p1.x, acc[2]);
            acc[3] = fmaf(ex, p1.y, acc[3]);
            acc[4] = fmaf(ex, p2.x, acc[4]);
            acc[5] = fmaf(ex, p2.y, acc[5]);
            acc[6] = fmaf(ex, p3.x, acc[6]);
            acc[7] = fmaf(ex, p3.y, acc[7]);
        }
        // reduce across the 8 groups (lanes differing in bits 3..5)
#pragma unroll
        for (int j = 0; j < 8; ++j) {
            acc[j] += __shfl_xor(acc[j], 8);
            acc[j] += __shfl_xor(acc[j], 16);
            acc[j] += __shfl_xor(acc[j], 32);
        }
        den += __shfl_xor(den, 8);
        den += __shfl_xor(den, 16);
        den += __shfl_xor(den, 32);
        float inv = 1.f / den;                 // full sum, counted once
        const float4 bv0 = *(const float4*)(bias + l * 8);
        const float4 bv1 = *(const float4*)(bias + l * 8 + 4);
        v[0] = fmaf(acc[0], inv, bv0.x);
        v[1] = fmaf(acc[1], inv, bv0.y);
        v[2] = fmaf(acc[2], inv, bv0.z);
        v[3] = fmaf(acc[3], inv, bv0.w);
        v[4] = fmaf(acc[4], inv, bv1.x);
        v[5] = fmaf(acc[5], inv, bv1.y);
        v[6] = fmaf(acc[6], inv, bv1.z);
        v[7] = fmaf(acc[7], inv, bv1.w);
        if (mode == 1) {
#pragma unroll
            for (int j = 0; j < 8; ++j) v[j] = fmaxf(v[j], 0.f);
            if (g == 0) {
                uint4 pk;
                pk.x = (unsigned)f2bf(v[0]) | ((unsigned)f2bf(v[1]) << 16);
                pk.y = (unsigned)f2bf(v[2]) | ((unsigned)f2bf(v[3]) << 16);
                pk.z = (unsigned)f2bf(v[4]) | ((unsigned)f2bf(v[5]) << 16);
                pk.w = (unsigned)f2bf(v[6]) | ((unsigned)f2bf(v[7]) << 16);
                *(uint4*)(out + (size_t)wave * NDIM + l * 8) = pk;
            }
        }
    }
    if (mode == 2) {
        if (g == 0) {
#pragma unroll
            for (int j = 0; j < 8; ++j) psum[wid][l * 8 + j] = v[j];
        }
        __syncthreads();
        if (threadIdx.x < NDIM) {
            float t = psum[0][threadIdx.x] + psum[1][threadIdx.x] +
                      psum[2][threadIdx.x] + psum[3][threadIdx.x];
            pool[(size_t)blockIdx.x * NDIM + threadIdx.x] = t;
        }
    }
}

// ---------------- final mean reduce over per-block partials ----------------
__global__ void mean_kernel(const float* __restrict__ pool, float* __restrict__ out,
                            int nb, float invn) {
    __shared__ float sm[4][NDIM];
    int lane = threadIdx.x & 63, wid = threadIdx.x >> 6;
    int row = blockIdx.x * 4 + wid;
    int stride = gridDim.x * 4;
    float s = 0.f;
    for (int i = row; i < nb; i += stride) s += pool[(long)i * NDIM + lane];
    sm[wid][lane] = s;
    __syncthreads();
    if (wid == 0) {
        float v = sm[0][lane] + sm[1][lane] + sm[2][lane] + sm[3][lane];
        atomicAdd(&out[lane], v * invn);
    }
}

extern "C" void kernel_launch(void* const* d_in, const int* in_sizes, int n_in,
                              void* d_out, int out_size, void* d_ws, size_t ws_size,
                              hipStream_t stream) {
    const float* x      = (const float*)d_in[0];
    const int*   eidx   = (const int*)d_in[1];
    const float* W1     = (const float*)d_in[2];
    const float* a_src1 = (const float*)d_in[3];
    const float* a_dst1 = (const float*)d_in[4];
    const float* b1     = (const float*)d_in[5];
    const float* W2     = (const float*)d_in[6];
    const float* a_src2 = (const float*)d_in[7];
    const float* a_dst2 = (const float*)d_in[8];
    const float* b2     = (const float*)d_in[9];
    float* out = (float*)d_out;

    const int N = in_sizes[0] / 20;      // 100000 (< 2^17, required by u32 part pack)
    const int E = in_sizes[1] / 2;       // 1000000
    const int* src = eidx;
    const int* dst = eidx + E;
    const int NB = (N + BNODES - 1) >> BSHIFT;   // 391

    // workspace layout (part NOT aliased with h: gemm1 runs concurrently now)
    char* ws = (char*)d_ws;
    unsigned char* h = (unsigned char*)ws;            // N*64 fp8 (6.4 MB)
    ushort* o   = (ushort*)(h + (size_t)N * NDIM);    // N*64 bf16 (12.8 MB)
    float* as_  = (float*)(o + (size_t)N * NDIM);     // N
    float* ad_  = as_ + N;                            // N
    int2*  offlen = (int2*)(ad_ + N);                 // N
    int*   csr  = (int*)(offlen + N);                 // NB*CCAP
    float* pool = (float*)(csr + (size_t)NB * CCAP);  // agg_blocks*64
    int*   bcur = (int*)(pool + (size_t)((N + 3) / 4) * NDIM);  // NB
    unsigned* part = (unsigned*)(bcur + NB + 32);     // NB*ECAP u32 (5.6 MB, dedicated)

    const int PB = (E + 4095) / 4096;         // 245 partition blocks
    const int gemm_blocks = (N + 63) / 64;    // 1563 (64 nodes/block)
    const int agg_blocks  = (N + 3) / 4;      // 25000

    // bcur zeroed (0-based cursors), then fused partition + gemm1
    hipMemsetAsync(bcur, 0, (size_t)NB * sizeof(int), stream);
    pg1_kernel<<<PB + gemm_blocks, 256, 0, stream>>>(
        src, dst, bcur, part, E, NB, PB,
        x, W1, a_src1, a_dst1, h, as_, ad_, N);
    csr_kernel<<<NB, 256, 0, stream>>>(bcur, part, csr, offlen, N);

    // layer 1 aggregation
    agg_kernel<<<agg_blocks, 256, 0, stream>>>(offlen, csr, as_, ad_, h, b1, o, pool, N, 1);

    // layer 2
    gemm_kernel<64, 64><<<gemm_blocks, 256, 0, stream>>>(o, W2, a_src2, a_dst2, h, as_, ad_, N);
    agg_kernel<<<agg_blocks, 256, 0, stream>>>(offlen, csr, as_, ad_, h, b2, o, pool, N, 2);

    // final mean reduce
    hipMemsetAsync(d_out, 0, (size_t)out_size * sizeof(float), stream);
    mean_kernel<<<64, 256, 0, stream>>>(pool, out, agg_blocks, 1.0f / (float)N);
}